// Round 12
// baseline (246.972 us; speedup 1.0000x reference)
//
#include <hip/hip_runtime.h>
#include <math.h>

#define N_NODES 50000
#define N_EDGES 800000
#define ETOT    (N_EDGES + N_NODES)
#define GEMM_TILES ((N_NODES + 63) / 64)      // 782 (covers 50048 rows)
#define NROWS 50048                            // gemm-written rows
#define TROWS 65536                            // gather-table rows (incl sentinel)
#define SENT_ROW 65535                         // sentinel: zero row, al=-1e30
#define NPART 8
#define PART_SIZE (N_NODES / NPART)           // 6250
#define CHUNK_EDGES 2048
#define NCHUNK ((ETOT + CHUNK_EDGES - 1) / CHUNK_EDGES)  // 416
#define SCAT_BLOCKS (NCHUNK * NPART)                      // 3328
// init_k geometry: fillArr zeroed (12,512 uint4) + srcs 0xFF (400,016 uint4)
#define FILL_UINT4 12512
#define CLEAR_UINT4 412528
#define CLEAR_BLOCKS ((CLEAR_UINT4 + 255) / 256)          // 1612
#define PREP_BLOCKS 16                                     // 8 per matrix

typedef _Float16 f16x8 __attribute__((ext_vector_type(8)));   // 16 B
typedef _Float16 f16x4 __attribute__((ext_vector_type(4)));   // 8 B
typedef _Float16 f16x2 __attribute__((ext_vector_type(2)));   // 4 B
typedef float    f32x4 __attribute__((ext_vector_type(4)));

// ---------------------------------------------------------------- init: clear + weight prep
// fillArr region -> 0 (real-edge slots start at 1; self-loop owns slot 0);
// srcs region -> 0xFFFF (born-sentinel pads). Weight prep: 16 trivial blocks,
// 8 loads -> one 16B store per thread (r7 lesson: never a deep serial tail).
// Bt layout, element (k,n):  Bt[n*128 + (((k>>3) ^ (n&7))<<3) + (k&7)]

__global__ void __launch_bounds__(256) init_k(uint4* __restrict__ clr,
                                              const float* __restrict__ W1,
                                              const float* __restrict__ Wmu,
                                              const float* __restrict__ Wls,
                                              _Float16* __restrict__ Bt1,
                                              _Float16* __restrict__ Bt2) {
    int bid = blockIdx.x;
    if (bid < CLEAR_BLOCKS) {
        int id = bid * 256 + threadIdx.x;
        if (id < CLEAR_UINT4) {
            unsigned f = (id < FILL_UINT4) ? 0u : 0xFFFFFFFFu;
            uint4 v;
            v.x = f; v.y = f; v.z = f; v.w = f;
            clr[id] = v;
        }
        return;
    }
    int pb = bid - CLEAR_BLOCKS;           // 0..15
    int which = pb >> 3;                   // 0 -> Bt1 (W1), 1 -> Bt2 ([Wmu|Wls])
    int idx = (pb & 7) * 256 + threadIdx.x;  // 0..2047 = (m, n)
    int n = idx & 127;
    int m = idx >> 7;                      // k-block: k = m*8 + j
    f16x8 v8;
#pragma unroll
    for (int j = 0; j < 8; ++j) {
        int k = m * 8 + j;
        float v = which ? ((n < 64) ? Wmu[k * 64 + n] : Wls[k * 64 + (n - 64)])
                        : W1[k * 128 + n];
        v8[j] = (_Float16)v;
    }
    _Float16* dst = which ? Bt2 : Bt1;
    *(f16x8*)&dst[n * 128 + ((m ^ (n & 7)) << 3)] = v8;
}

// ---------------------------------------------------------------- scatter body (partitioned)
// Atomic-throughput-bound (r9). Self-loops (e >= N_EDGES) take slot 0
// deterministically — NO atomic (-50K of 850K). Real edges: slot =
// 1 + atomicAdd(fillArr[d]) with fillArr zero-init. cnt = fill+1 unchanged.

__device__ __forceinline__ void scatter_body(int sbid, const int* __restrict__ ei,
                                             int* __restrict__ fillArr,
                                             unsigned short* __restrict__ srcs) {
    int part = sbid & (NPART - 1);
    int chunk = sbid >> 3;
    int lo = part * PART_SIZE, hi = lo + PART_SIZE;
    int base = chunk * CHUNK_EDGES + threadIdx.x;
#pragma unroll
    for (int it = 0; it < CHUNK_EDGES / 256; ++it) {
        int e = base + it * 256;
        if (e >= ETOT) break;
        int d = (e < N_EDGES) ? ei[N_EDGES + e] : (e - N_EDGES);
        if (d >= lo && d < hi) {
            if (e < N_EDGES) {
                int pos = (d << 6) + 1 + atomicAdd(&fillArr[d], 1);
                srcs[pos] = (unsigned short)ei[e];
            } else {
                srcs[d << 6] = (unsigned short)d;   // self-loop: slot 0, no atomic
            }
        }
    }
}

// ---------------------------------------------------------------- MFMA GEMM pieces
// B pre-transposed/swizzled in global (32 KB fp16, fits per-CU L1). No Bsh,
// no transpose, no barriers (Cst slices per-wave-private). 16 KB LDS.

__device__ __forceinline__ void mfma_tile(const f16x8 a[4], const _Float16* __restrict__ Bt,
                                          f32x4 acc[8], int l) {
    int i16 = l & 15, q = l >> 4;
#pragma unroll
    for (int tt = 0; tt < 8; ++tt) acc[tt] = (f32x4){0.f, 0.f, 0.f, 0.f};
#pragma unroll
    for (int kb = 0; kb < 4; ++kb) {
#pragma unroll
        for (int tt = 0; tt < 8; ++tt) {
            int n = tt * 16 + i16;
            int gs = (kb * 4 + q) ^ (n & 7);
            f16x8 b = *(const f16x8*)&Bt[n * 128 + gs * 8];
            acc[tt] = __builtin_amdgcn_mfma_f32_16x16x32_f16(a[kb], b, acc[tt], 0, 0, 0);
        }
    }
}

__device__ __forceinline__ void store_C(const f32x4 acc[8], _Float16* cs,
                                        _Float16* __restrict__ C, int r0, int l) {
    int i16 = l & 15, q = l >> 4;
#pragma unroll
    for (int tt = 0; tt < 8; ++tt)
#pragma unroll
        for (int r = 0; r < 4; ++r)
            cs[(q * 4 + r) * 128 + tt * 16 + i16] = (_Float16)acc[tt][r];
#pragma unroll
    for (int u = 0; u < 4; ++u) {
        int idx = u * 64 + l;
        int rr = idx >> 4, cc = idx & 15;
        f16x8 v = ((f16x8*)cs)[idx];
        if (r0 + rr >= N_NODES) v = (f16x8)(_Float16)0.f;
        ((f16x8*)(C + (size_t)(r0 + rr) * 128))[cc] = v;
    }
}

// g1s: blocks [0, SCAT_BLOCKS) = partitioned scatter (the ~45us long pole —
// FIRST in grid order so it starts at t=0); blocks beyond = gemm1 (x@W1 +
// fused attn1 epilogue) filling in behind. 16 KB LDS keeps scatter occupancy
// (r11: 35%, fusion net +5.5us vs serial).
__global__ void __launch_bounds__(256) g1s_k(const float* __restrict__ A,
                                             const _Float16* __restrict__ Btg,
                                             const float* __restrict__ att_l,
                                             const float* __restrict__ att_r,
                                             _Float16* __restrict__ C,
                                             float* __restrict__ al,
                                             float* __restrict__ ar,
                                             const int* __restrict__ ei,
                                             int* __restrict__ fillArr,
                                             unsigned short* __restrict__ srcs) {
    __shared__ _Float16 Cst[4][16 * 128];
    if (blockIdx.x < SCAT_BLOCKS) {
        scatter_body(blockIdx.x, ei, fillArr, srcs);
        return;
    }
    int tile = blockIdx.x - SCAT_BLOCKS;
    int t = threadIdx.x;
    int wave = t >> 6, l = t & 63;
    int i16 = l & 15, q = l >> 4;
    float attL[8], attR[8];
#pragma unroll
    for (int tt = 0; tt < 8; ++tt) {
        int col = tt * 16 + i16;
        attL[tt] = att_l[col];
        attR[tt] = att_r[col];
    }
    int r0 = tile * 64 + wave * 16;
    const float* ar_ = A + (size_t)min(r0 + i16, N_NODES - 1) * 128;
    f16x8 a[4];
#pragma unroll
    for (int kb = 0; kb < 4; ++kb) {
        float4 u = ((const float4*)(ar_ + kb * 32 + q * 8))[0];
        float4 v = ((const float4*)(ar_ + kb * 32 + q * 8))[1];
        f16x8 t8;
        t8[0] = (_Float16)u.x; t8[1] = (_Float16)u.y;
        t8[2] = (_Float16)u.z; t8[3] = (_Float16)u.w;
        t8[4] = (_Float16)v.x; t8[5] = (_Float16)v.y;
        t8[6] = (_Float16)v.z; t8[7] = (_Float16)v.w;
        a[kb] = t8;
    }
    f32x4 acc[8];
    mfma_tile(a, Btg, acc, l);
    store_C(acc, &Cst[wave][0], C, r0, l);
    float pl[2][4], pr[2][4];
#pragma unroll
    for (int h = 0; h < 2; ++h)
#pragma unroll
        for (int r = 0; r < 4; ++r) {
            float sl = 0.f, sr = 0.f;
#pragma unroll
            for (int k = 0; k < 4; ++k) {
                float v = acc[h * 4 + k][r];
                sl += v * attL[h * 4 + k];
                sr += v * attR[h * 4 + k];
            }
            pl[h][r] = sl; pr[h][r] = sr;
        }
#pragma unroll
    for (int m = 1; m < 16; m <<= 1) {
#pragma unroll
        for (int h = 0; h < 2; ++h)
#pragma unroll
            for (int r = 0; r < 4; ++r) {
                pl[h][r] += __shfl_xor(pl[h][r], m);
                pr[h][r] += __shfl_xor(pr[h][r], m);
            }
    }
    if (i16 == 0) {
#pragma unroll
        for (int h = 0; h < 2; ++h)
#pragma unroll
            for (int r = 0; r < 4; ++r) {
                int row = r0 + q * 4 + r;
                al[row * 2 + h] = pl[h][r];
                ar[row * 2 + h] = pr[h][r];
            }
    }
    if (tile == 0) {
        if (t < 16) ((f16x8*)(C + (size_t)SENT_ROW * 128))[t] = (f16x8)(_Float16)0.f;
        else if (t == 16) {
            al[SENT_ROW * 2] = -1e30f; al[SENT_ROW * 2 + 1] = -1e30f;
            ar[SENT_ROW * 2] = 0.f;    ar[SENT_ROW * 2 + 1] = 0.f;
        }
    }
}

// gemm2: A fp16 h2, B = Bt2 (pre-swizzled [Wmu|Wls]); fused attn23 epilogue.
__global__ void __launch_bounds__(256) gemm2_k(const _Float16* __restrict__ A,
                                               const _Float16* __restrict__ Btg,
                                               const float* __restrict__ attlmu,
                                               const float* __restrict__ attrmu,
                                               const float* __restrict__ attlls,
                                               const float* __restrict__ attrls,
                                               _Float16* __restrict__ C,
                                               float* __restrict__ alc,
                                               float* __restrict__ arc) {
    __shared__ _Float16 Cst[4][16 * 128];
    int t = threadIdx.x;
    int wave = t >> 6, l = t & 63;
    int i16 = l & 15, q = l >> 4;
    float attL[8], attR[8];
#pragma unroll
    for (int tt = 0; tt < 8; ++tt) {
        int col = tt * 16 + i16;
        const float* la = (tt < 4) ? attlmu : attlls;
        const float* ra = (tt < 4) ? attrmu : attrls;
        attL[tt] = la[col & 63];
        attR[tt] = ra[col & 63];
    }
    int r0 = blockIdx.x * 64 + wave * 16;
    const _Float16* ar_ = A + (size_t)min(r0 + i16, N_NODES - 1) * 128;
    f16x8 a[4];
#pragma unroll
    for (int kb = 0; kb < 4; ++kb)
        a[kb] = *(const f16x8*)(ar_ + kb * 32 + q * 8);
    f32x4 acc[8];
    mfma_tile(a, Btg, acc, l);
    store_C(acc, &Cst[wave][0], C, r0, l);
    float pl[4][4], pr[4][4];
#pragma unroll
    for (int g = 0; g < 4; ++g)
#pragma unroll
        for (int r = 0; r < 4; ++r) {
            float sl = 0.f, sr = 0.f;
#pragma unroll
            for (int k = 0; k < 2; ++k) {
                float v = acc[g * 2 + k][r];
                sl += v * attL[g * 2 + k];
                sr += v * attR[g * 2 + k];
            }
            pl[g][r] = sl; pr[g][r] = sr;
        }
#pragma unroll
    for (int m = 1; m < 16; m <<= 1) {
#pragma unroll
        for (int g = 0; g < 4; ++g)
#pragma unroll
            for (int r = 0; r < 4; ++r) {
                pl[g][r] += __shfl_xor(pl[g][r], m);
                pr[g][r] += __shfl_xor(pr[g][r], m);
            }
    }
    if (i16 == 0) {
#pragma unroll
        for (int g = 0; g < 4; ++g)
#pragma unroll
            for (int r = 0; r < 4; ++r) {
                int row = r0 + q * 4 + r;
                alc[row * 4 + g] = pl[g][r];
                arc[row * 4 + g] = pr[g][r];
            }
    }
    if (blockIdx.x == 0) {
        if (t < 16) ((f16x8*)(C + (size_t)SENT_ROW * 128))[t] = (f16x8)(_Float16)0.f;
        else if (t == 16) {
#pragma unroll
            for (int g = 0; g < 4; ++g) {
                alc[SENT_ROW * 4 + g] = -1e30f;
                arc[SENT_ROW * 4 + g] = 0.f;
            }
        }
    }
}

// ---------------------------------------------------------------- edge aggregation
// 8 lanes per edge, 8 edges/iter, 2-deep pipeline with rotation by movs.
// Lessons: (r3) big unroll -> VGPR 48, occupancy -16pt; (r5) persistent waves
// -22pt; (r7) alien-work fusion wrecks codegen. Short blocks, small body.

__device__ __forceinline__ float sigmoidf_fast(float x) {
    return 1.f / (1.f + __expf(-x));
}

__device__ __forceinline__ float dot8_f16(f16x8 a, f16x8 b) {
    float part = 0.f;
#if __has_builtin(__builtin_amdgcn_fdot2)
    f16x2* pa = (f16x2*)&a;
    f16x2* pb = (f16x2*)&b;
#pragma unroll
    for (int kk = 0; kk < 4; ++kk)
        part = __builtin_amdgcn_fdot2(pa[kk], pb[kk], part, false);
#else
#pragma unroll
    for (int kk = 0; kk < 8; ++kk) part += (float)a[kk] * (float)b[kk];
#endif
    return part;
}

__device__ __forceinline__ float leaky_clamp(float x) {
    return __builtin_amdgcn_fmed3f(x, 0.2f * x, 60.f);
}

__global__ void __launch_bounds__(256) edge1_k(const _Float16* __restrict__ h1,
                                               const float* __restrict__ al,
                                               const float* __restrict__ ar,
                                               const int* __restrict__ fillArr,
                                               const unsigned short* __restrict__ srcs,
                                               const float* __restrict__ b1,
                                               _Float16* __restrict__ h2o) {
    int i = (blockIdx.x * blockDim.x + threadIdx.x) >> 6;
    int l = threadIdx.x & 63;
    if (i >= N_NODES) return;
    int c16 = l & 7;
    int head = c16 >> 2;
    int sub = l >> 3;

    const f16x8* rowi = (const f16x8*)(h1 + (size_t)i * 128);
    f16x8 hiA = rowi[c16 * 2], hiB = rowi[c16 * 2 + 1];
    float ari = ar[i * 2 + head];
    int cnt = fillArr[i] + 1;
    int start = i << 6;
    int end = start + ((cnt + 7) & ~7);
    float s = 0.f;
    float o[16];
#pragma unroll
    for (int k = 0; k < 16; ++k) o[k] = 0.f;

    int p = start + sub + 16;
    int j0 = srcs[start + sub];
    int j1 = srcs[start + sub + 8];
    const f16x8* r0p = (const f16x8*)(h1 + (size_t)j0 * 128);
    const f16x8* r1p = (const f16x8*)(h1 + (size_t)j1 * 128);
    f16x8 qA0 = r0p[c16 * 2], qB0 = r0p[c16 * 2 + 1];
    f16x8 qA1 = r1p[c16 * 2], qB1 = r1p[c16 * 2 + 1];
    float a0 = al[j0 * 2 + head];
    float a1 = al[j1 * 2 + head];

    for (int pb = start; pb < end; pb += 8) {
        float part = dot8_f16(hiA, qA0) + dot8_f16(hiB, qB0);
        part += __shfl_xor(part, 1);
        part += __shfl_xor(part, 2);
        float a = (a0 + ari) * sigmoidf_fast(part);
        float w = __expf(leaky_clamp(a));
        s += w;
#pragma unroll
        for (int k = 0; k < 8; ++k) o[k] += w * (float)qA0[k];
#pragma unroll
        for (int k = 0; k < 8; ++k) o[8 + k] += w * (float)qB0[k];
        qA0 = qA1; qB0 = qB1; a0 = a1;
        int jn = srcs[p]; p += 8;
        const f16x8* rn = (const f16x8*)(h1 + (size_t)jn * 128);
        qA1 = rn[c16 * 2]; qB1 = rn[c16 * 2 + 1];
        a1 = al[jn * 2 + head];
    }
#pragma unroll
    for (int m = 8; m < 64; m <<= 1) {
        s += __shfl_xor(s, m);
#pragma unroll
        for (int k = 0; k < 16; ++k) o[k] += __shfl_xor(o[k], m);
    }
    if (l < 8) {
        float inv = 1.f / (s + 1e-16f);
        f16x8 rA, rB;
#pragma unroll
        for (int k = 0; k < 16; ++k) {
            float r = o[k] * inv + b1[l * 16 + k];
            r = (r > 0.f) ? r : (__expf(r) - 1.f);
            if (k < 8) rA[k] = (_Float16)r; else rB[k - 8] = (_Float16)r;
        }
        f16x8* dst = (f16x8*)(h2o + (size_t)i * 128);
        dst[l * 2] = rA;
        dst[l * 2 + 1] = rB;
    }
}

__global__ void __launch_bounds__(256) edge23_k(const _Float16* __restrict__ hcat,
                                                const float* __restrict__ alc,
                                                const float* __restrict__ arc,
                                                const int* __restrict__ fillArr,
                                                const unsigned short* __restrict__ srcs,
                                                const float* __restrict__ bmu,
                                                const float* __restrict__ bls,
                                                float* __restrict__ out) {
    int i = (blockIdx.x * blockDim.x + threadIdx.x) >> 6;
    int l = threadIdx.x & 63;
    if (i >= N_NODES) return;
    int c16 = l & 7;
    int g = c16 >> 1;
    int sub = l >> 3;

    const f16x8* rowi = (const f16x8*)(hcat + (size_t)i * 128);
    f16x8 hiA = rowi[c16 * 2], hiB = rowi[c16 * 2 + 1];
    float ari = arc[i * 4 + g];
    int cnt = fillArr[i] + 1;
    int start = i << 6;
    int end = start + ((cnt + 7) & ~7);
    float s = 0.f;
    float o[16];
#pragma unroll
    for (int k = 0; k < 16; ++k) o[k] = 0.f;

    int p = start + sub + 16;
    int j0 = srcs[start + sub];
    int j1 = srcs[start + sub + 8];
    const f16x8* r0p = (const f16x8*)(hcat + (size_t)j0 * 128);
    const f16x8* r1p = (const f16x8*)(hcat + (size_t)j1 * 128);
    f16x8 qA0 = r0p[c16 * 2], qB0 = r0p[c16 * 2 + 1];
    f16x8 qA1 = r1p[c16 * 2], qB1 = r1p[c16 * 2 + 1];
    float a0 = alc[j0 * 4 + g];
    float a1 = alc[j1 * 4 + g];

    for (int pb = start; pb < end; pb += 8) {
        float part = dot8_f16(hiA, qA0) + dot8_f16(hiB, qB0);
        part += __shfl_xor(part, 1);
        float a = (a0 + ari) * sigmoidf_fast(part);
        float w = __expf(leaky_clamp(a));
        s += w;
#pragma unroll
        for (int k = 0; k < 8; ++k) o[k] += w * (float)qA0[k];
#pragma unroll
        for (int k = 0; k < 8; ++k) o[8 + k] += w * (float)qB0[k];
        qA0 = qA1; qB0 = qB1; a0 = a1;
        int jn = srcs[p]; p += 8;
        const f16x8* rn = (const f16x8*)(hcat + (size_t)jn * 128);
        qA1 = rn[c16 * 2]; qB1 = rn[c16 * 2 + 1];
        a1 = alc[jn * 4 + g];
    }
#pragma unroll
    for (int m = 8; m < 64; m <<= 1) {
        s += __shfl_xor(s, m);
#pragma unroll
        for (int k = 0; k < 16; ++k) o[k] += __shfl_xor(o[k], m);
    }
    if (l < 8) {
        float inv = 1.f / (s + 1e-16f);
        int br = l >> 2;
        int cIn = (l & 3) * 16;
        const float* b = br ? bls : bmu;
        float* dst = out + (size_t)br * (N_NODES * 64) + (size_t)i * 64 + cIn;
#pragma unroll
        for (int v4 = 0; v4 < 4; ++v4) {
            float4 bv = ((const float4*)(b + cIn))[v4];
            float4 r;
            r.x = o[v4 * 4 + 0] * inv + bv.x;
            r.y = o[v4 * 4 + 1] * inv + bv.y;
            r.z = o[v4 * 4 + 2] * inv + bv.z;
            r.w = o[v4 * 4 + 3] * inv + bv.w;
            ((float4*)dst)[v4] = r;
        }
    }
}

// ---------------------------------------------------------------- launcher

extern "C" void kernel_launch(void* const* d_in, const int* in_sizes, int n_in,
                              void* d_out, int out_size, void* d_ws, size_t ws_size,
                              hipStream_t stream) {
    const float* x      = (const float*)d_in[0];
    const int*   ei     = (const int*)d_in[1];
    const float* W1     = (const float*)d_in[2];
    const float* att_l1 = (const float*)d_in[3];
    const float* att_r1 = (const float*)d_in[4];
    const float* b1     = (const float*)d_in[5];
    const float* Wmu    = (const float*)d_in[6];
    const float* attlmu = (const float*)d_in[7];
    const float* attrmu = (const float*)d_in[8];
    const float* bmu    = (const float*)d_in[9];
    const float* Wls    = (const float*)d_in[10];
    const float* attlls = (const float*)d_in[11];
    const float* attrls = (const float*)d_in[12];
    const float* bls    = (const float*)d_in[13];
    float* out = (float*)d_out;

    _Float16* h1   = (_Float16*)d_ws;                      // TROWS*128 halfs
    _Float16* hcat = h1 + (size_t)TROWS * 128;             // TROWS*128 halfs
    _Float16* h2   = hcat + (size_t)TROWS * 128;           // NROWS*128 halfs
    float* al1   = (float*)(h2 + (size_t)NROWS * 128);     // TROWS*2
    float* ar1   = al1 + TROWS * 2;                        // TROWS*2
    float* alc   = ar1 + TROWS * 2;                        // TROWS*4
    float* arc   = alc + TROWS * 4;                        // TROWS*4
    // fillArr and srcs contiguous: init_k zeroes fillArr (slot counter base 0)
    // and 0xFF-fills srcs (born-sentinel) in one pass.
    int* fillArr = (int*)(arc + TROWS * 4);                // 50,048 ints
    unsigned short* srcs = (unsigned short*)(fillArr + 50048);  // 3,200,128 ushorts
    _Float16* Bt1 = (_Float16*)(srcs + 3200128);           // 128*128 halfs (32 KB)
    _Float16* Bt2 = Bt1 + 128 * 128;                       // 128*128 halfs (32 KB)

    // clear (fillArr=0, srcs=0xFF) + one-time weight transpose/swizzle prep
    init_k<<<CLEAR_BLOCKS + PREP_BLOCKS, 256, 0, stream>>>((uint4*)fillArr,
                                                           W1, Wmu, Wls, Bt1, Bt2);

    // fused: partitioned scatter FIRST (long pole, blocks 0..3327) + gemm1
    g1s_k<<<SCAT_BLOCKS + GEMM_TILES, 256, 0, stream>>>(x, Bt1, att_l1, att_r1,
                                                        h1, al1, ar1,
                                                        ei, fillArr, srcs);

    int nblocks = (N_NODES + 3) / 4;       // edge kernels: 4 waves (nodes) / block
    edge1_k<<<nblocks, 256, 0, stream>>>(h1, al1, ar1, fillArr, srcs, b1, h2);

    gemm2_k<<<GEMM_TILES, 256, 0, stream>>>(h2, Bt2, attlmu, attrmu, attlls, attrls,
                                            hcat, alc, arc);
    edge23_k<<<nblocks, 256, 0, stream>>>(hcat, alc, arc, fillArr, srcs, bmu, bls, out);
}

// Round 13
// 246.722 us; speedup vs baseline: 1.0010x; 1.0010x over previous
//
#include <hip/hip_runtime.h>
#include <math.h>

#define N_NODES 50000
#define N_EDGES 800000
#define ETOT    (N_EDGES + N_NODES)
#define GEMM_TILES ((N_NODES + 63) / 64)      // 782 (covers 50048 rows)
#define NROWS 50048                            // gemm-written rows
#define TROWS 65536                            // gather-table rows (incl sentinel)
#define SENT_ROW 65535                         // sentinel: zero row, al=-1e30
#define NPART 8
#define PART_SIZE (N_NODES / NPART)           // 6250
#define CHUNK_EDGES 2048
#define NCHUNK ((ETOT + CHUNK_EDGES - 1) / CHUNK_EDGES)  // 416
// init_k geometry: clear fillArr+srcs (6,600,448 B = 412,528 uint4) + weight prep
#define CLEAR_UINT4 412528
#define CLEAR_BLOCKS ((CLEAR_UINT4 + 255) / 256)          // 1612
#define PREP_BLOCKS 16                                     // 8 per matrix

typedef _Float16 f16x8 __attribute__((ext_vector_type(8)));   // 16 B
typedef _Float16 f16x4 __attribute__((ext_vector_type(4)));   // 8 B
typedef _Float16 f16x2 __attribute__((ext_vector_type(2)));   // 4 B
typedef float    f32x4 __attribute__((ext_vector_type(4)));
typedef float    f32x2 __attribute__((ext_vector_type(2)));

// ---------------------------------------------------------------- init: clear + weight prep
// Clear (0xFF) fillArr+srcs AND one-time weight transpose+swizzle (16 trivial
// blocks, 8 loads -> one 16B store per thread; r7 lesson: never as a deep
// serial tail inside another kernel).
// Bt layout, element (k,n):  Bt[n*128 + (((k>>3) ^ (n&7))<<3) + (k&7)]

__global__ void __launch_bounds__(256) init_k(uint4* __restrict__ clr,
                                              const float* __restrict__ W1,
                                              const float* __restrict__ Wmu,
                                              const float* __restrict__ Wls,
                                              _Float16* __restrict__ Bt1,
                                              _Float16* __restrict__ Bt2) {
    int bid = blockIdx.x;
    if (bid < CLEAR_BLOCKS) {
        int id = bid * 256 + threadIdx.x;
        if (id < CLEAR_UINT4) {
            uint4 v;
            v.x = 0xFFFFFFFFu; v.y = 0xFFFFFFFFu; v.z = 0xFFFFFFFFu; v.w = 0xFFFFFFFFu;
            clr[id] = v;
        }
        return;
    }
    int pb = bid - CLEAR_BLOCKS;           // 0..15
    int which = pb >> 3;                   // 0 -> Bt1 (W1), 1 -> Bt2 ([Wmu|Wls])
    int idx = (pb & 7) * 256 + threadIdx.x;  // 0..2047 = (m, n)
    int n = idx & 127;
    int m = idx >> 7;                      // k-block: k = m*8 + j
    f16x8 v8;
#pragma unroll
    for (int j = 0; j < 8; ++j) {
        int k = m * 8 + j;
        float v = which ? ((n < 64) ? Wmu[k * 64 + n] : Wls[k * 64 + (n - 64)])
                        : W1[k * 128 + n];
        v8[j] = (_Float16)v;
    }
    _Float16* dst = which ? Bt2 : Bt1;
    *(f16x8*)&dst[n * 128 + ((m ^ (n & 7)) << 3)] = v8;
}

// ---------------------------------------------------------------- scatter body (partitioned)
// Round-9 finding: scatter is bound by device-atomic throughput in ANY form;
// partitioned beats single-pass via write locality. We HIDE the scatter by
// overlapping it with gemm1 (independent work) in one dispatch. R12 lesson:
// gemm (long) blocks FIRST, scatter (short) blocks backfill — LPT packing;
// scatter-first pinned g1s at 59us vs 49-58 spread.

__device__ __forceinline__ void scatter_body(int sbid, const int* __restrict__ ei,
                                             int* __restrict__ fillArr,
                                             unsigned short* __restrict__ srcs) {
    int part = sbid & (NPART - 1);
    int chunk = sbid >> 3;
    int lo = part * PART_SIZE, hi = lo + PART_SIZE;
    int base = chunk * CHUNK_EDGES + threadIdx.x;
#pragma unroll
    for (int it = 0; it < CHUNK_EDGES / 256; ++it) {
        int e = base + it * 256;
        if (e >= ETOT) break;
        int d = (e < N_EDGES) ? ei[N_EDGES + e] : (e - N_EDGES);
        if (d >= lo && d < hi) {
            int s = (e < N_EDGES) ? ei[e] : d;
            int pos = (d << 6) + (atomicAdd(&fillArr[d], 1) + 1);
            srcs[pos] = (unsigned short)s;
        }
    }
}

// ---------------------------------------------------------------- MFMA GEMM pieces
// B pre-transposed/swizzled in global (32 KB fp16, fits per-CU L1). No Bsh,
// no transpose, no barriers (Cst slices per-wave-private). 16 KB LDS.

__device__ __forceinline__ void mfma_tile(const f16x8 a[4], const _Float16* __restrict__ Bt,
                                          f32x4 acc[8], int l) {
    int i16 = l & 15, q = l >> 4;
#pragma unroll
    for (int tt = 0; tt < 8; ++tt) acc[tt] = (f32x4){0.f, 0.f, 0.f, 0.f};
#pragma unroll
    for (int kb = 0; kb < 4; ++kb) {
#pragma unroll
        for (int tt = 0; tt < 8; ++tt) {
            int n = tt * 16 + i16;
            int gs = (kb * 4 + q) ^ (n & 7);
            f16x8 b = *(const f16x8*)&Bt[n * 128 + gs * 8];
            acc[tt] = __builtin_amdgcn_mfma_f32_16x16x32_f16(a[kb], b, acc[tt], 0, 0, 0);
        }
    }
}

__device__ __forceinline__ void store_C(const f32x4 acc[8], _Float16* cs,
                                        _Float16* __restrict__ C, int r0, int l) {
    int i16 = l & 15, q = l >> 4;
#pragma unroll
    for (int tt = 0; tt < 8; ++tt)
#pragma unroll
        for (int r = 0; r < 4; ++r)
            cs[(q * 4 + r) * 128 + tt * 16 + i16] = (_Float16)acc[tt][r];
#pragma unroll
    for (int u = 0; u < 4; ++u) {
        int idx = u * 64 + l;
        int rr = idx >> 4, cc = idx & 15;
        f16x8 v = ((f16x8*)cs)[idx];
        if (r0 + rr >= N_NODES) v = (f16x8)(_Float16)0.f;
        ((f16x8*)(C + (size_t)(r0 + rr) * 128))[cc] = v;
    }
}

// g1s: blocks [0, GEMM_TILES) = gemm1 (x@W1 + fused attn1 epilogue, LONG
// blocks first = LPT); blocks beyond = partitioned scatter backfilling.
// 16 KB LDS keeps scatter occupancy (r11: 35%, fusion net +5.5us vs serial).
__global__ void __launch_bounds__(256) g1s_k(const float* __restrict__ A,
                                             const _Float16* __restrict__ Btg,
                                             const float* __restrict__ att_l,
                                             const float* __restrict__ att_r,
                                             _Float16* __restrict__ C,
                                             float* __restrict__ al,
                                             float* __restrict__ ar,
                                             const int* __restrict__ ei,
                                             int* __restrict__ fillArr,
                                             unsigned short* __restrict__ srcs) {
    __shared__ _Float16 Cst[4][16 * 128];
    if (blockIdx.x >= GEMM_TILES) {
        scatter_body(blockIdx.x - GEMM_TILES, ei, fillArr, srcs);
        return;
    }
    int t = threadIdx.x;
    int wave = t >> 6, l = t & 63;
    int i16 = l & 15, q = l >> 4;
    float attL[8], attR[8];
#pragma unroll
    for (int tt = 0; tt < 8; ++tt) {
        int col = tt * 16 + i16;
        attL[tt] = att_l[col];
        attR[tt] = att_r[col];
    }
    int r0 = blockIdx.x * 64 + wave * 16;
    const float* ar_ = A + (size_t)min(r0 + i16, N_NODES - 1) * 128;
    f16x8 a[4];
#pragma unroll
    for (int kb = 0; kb < 4; ++kb) {
        float4 u = ((const float4*)(ar_ + kb * 32 + q * 8))[0];
        float4 v = ((const float4*)(ar_ + kb * 32 + q * 8))[1];
        f16x8 t8;
        t8[0] = (_Float16)u.x; t8[1] = (_Float16)u.y;
        t8[2] = (_Float16)u.z; t8[3] = (_Float16)u.w;
        t8[4] = (_Float16)v.x; t8[5] = (_Float16)v.y;
        t8[6] = (_Float16)v.z; t8[7] = (_Float16)v.w;
        a[kb] = t8;
    }
    f32x4 acc[8];
    mfma_tile(a, Btg, acc, l);
    store_C(acc, &Cst[wave][0], C, r0, l);
    float pl[2][4], pr[2][4];
#pragma unroll
    for (int h = 0; h < 2; ++h)
#pragma unroll
        for (int r = 0; r < 4; ++r) {
            float sl = 0.f, sr = 0.f;
#pragma unroll
            for (int k = 0; k < 4; ++k) {
                float v = acc[h * 4 + k][r];
                sl += v * attL[h * 4 + k];
                sr += v * attR[h * 4 + k];
            }
            pl[h][r] = sl; pr[h][r] = sr;
        }
#pragma unroll
    for (int m = 1; m < 16; m <<= 1) {
#pragma unroll
        for (int h = 0; h < 2; ++h)
#pragma unroll
            for (int r = 0; r < 4; ++r) {
                pl[h][r] += __shfl_xor(pl[h][r], m);
                pr[h][r] += __shfl_xor(pr[h][r], m);
            }
    }
    if (i16 == 0) {
#pragma unroll
        for (int h = 0; h < 2; ++h)
#pragma unroll
            for (int r = 0; r < 4; ++r) {
                int row = r0 + q * 4 + r;
                al[row * 2 + h] = pl[h][r];
                ar[row * 2 + h] = pr[h][r];
            }
    }
    if (blockIdx.x == 0) {
        if (t < 16) ((f16x8*)(C + (size_t)SENT_ROW * 128))[t] = (f16x8)(_Float16)0.f;
        else if (t == 16) {
            al[SENT_ROW * 2] = -1e30f; al[SENT_ROW * 2 + 1] = -1e30f;
            ar[SENT_ROW * 2] = 0.f;    ar[SENT_ROW * 2 + 1] = 0.f;
        }
    }
}

// gemm2: A fp16 h2, B = Bt2 (pre-swizzled [Wmu|Wls]); fused attn23 epilogue.
__global__ void __launch_bounds__(256) gemm2_k(const _Float16* __restrict__ A,
                                               const _Float16* __restrict__ Btg,
                                               const float* __restrict__ attlmu,
                                               const float* __restrict__ attrmu,
                                               const float* __restrict__ attlls,
                                               const float* __restrict__ attrls,
                                               _Float16* __restrict__ C,
                                               float* __restrict__ alc,
                                               float* __restrict__ arc) {
    __shared__ _Float16 Cst[4][16 * 128];
    int t = threadIdx.x;
    int wave = t >> 6, l = t & 63;
    int i16 = l & 15, q = l >> 4;
    float attL[8], attR[8];
#pragma unroll
    for (int tt = 0; tt < 8; ++tt) {
        int col = tt * 16 + i16;
        const float* la = (tt < 4) ? attlmu : attlls;
        const float* ra = (tt < 4) ? attrmu : attrls;
        attL[tt] = la[col & 63];
        attR[tt] = ra[col & 63];
    }
    int r0 = blockIdx.x * 64 + wave * 16;
    const _Float16* ar_ = A + (size_t)min(r0 + i16, N_NODES - 1) * 128;
    f16x8 a[4];
#pragma unroll
    for (int kb = 0; kb < 4; ++kb)
        a[kb] = *(const f16x8*)(ar_ + kb * 32 + q * 8);
    f32x4 acc[8];
    mfma_tile(a, Btg, acc, l);
    store_C(acc, &Cst[wave][0], C, r0, l);
    float pl[4][4], pr[4][4];
#pragma unroll
    for (int g = 0; g < 4; ++g)
#pragma unroll
        for (int r = 0; r < 4; ++r) {
            float sl = 0.f, sr = 0.f;
#pragma unroll
            for (int k = 0; k < 2; ++k) {
                float v = acc[g * 2 + k][r];
                sl += v * attL[g * 2 + k];
                sr += v * attR[g * 2 + k];
            }
            pl[g][r] = sl; pr[g][r] = sr;
        }
#pragma unroll
    for (int m = 1; m < 16; m <<= 1) {
#pragma unroll
        for (int g = 0; g < 4; ++g)
#pragma unroll
            for (int r = 0; r < 4; ++r) {
                pl[g][r] += __shfl_xor(pl[g][r], m);
                pr[g][r] += __shfl_xor(pr[g][r], m);
            }
    }
    if (i16 == 0) {
#pragma unroll
        for (int g = 0; g < 4; ++g)
#pragma unroll
            for (int r = 0; r < 4; ++r) {
                int row = r0 + q * 4 + r;
                alc[row * 4 + g] = pl[g][r];
                arc[row * 4 + g] = pr[g][r];
            }
    }
    if (blockIdx.x == 0) {
        if (t < 16) ((f16x8*)(C + (size_t)SENT_ROW * 128))[t] = (f16x8)(_Float16)0.f;
        else if (t == 16) {
#pragma unroll
            for (int g = 0; g < 4; ++g) {
                alc[SENT_ROW * 4 + g] = -1e30f;
                arc[SENT_ROW * 4 + g] = 0.f;
            }
        }
    }
}

// ---------------------------------------------------------------- edge aggregation
// 8 lanes per edge, 8 edges/iter, 2-deep pipeline with rotation by movs.
// ROUND-13: o[] accumulation packed as f32x2 (8 x v_pk_fma_f32 instead of
// 16 x v_fmac_f32) — the dominant VALU cost of the inner loop. Accumulation
// stays f32 (w reaches e^60; fp16 impossible). Index maps in epilogue are
// compile-time under unroll. Lessons: (r3) big unroll -> occupancy -16pt;
// (r5) persistent waves -22pt; (r7) alien-work fusion wrecks codegen.

__device__ __forceinline__ float sigmoidf_fast(float x) {
    return 1.f / (1.f + __expf(-x));
}

__device__ __forceinline__ float dot8_f16(f16x8 a, f16x8 b) {
    float part = 0.f;
#if __has_builtin(__builtin_amdgcn_fdot2)
    f16x2* pa = (f16x2*)&a;
    f16x2* pb = (f16x2*)&b;
#pragma unroll
    for (int kk = 0; kk < 4; ++kk)
        part = __builtin_amdgcn_fdot2(pa[kk], pb[kk], part, false);
#else
#pragma unroll
    for (int kk = 0; kk < 8; ++kk) part += (float)a[kk] * (float)b[kk];
#endif
    return part;
}

__device__ __forceinline__ float leaky_clamp(float x) {
    return __builtin_amdgcn_fmed3f(x, 0.2f * x, 60.f);
}

// o2[k>>1][k&1] holds old o[k] (A half, k<8); o2[4+...] the B half.
#define OVAL(K) ((K) < 8 ? o2[(K) >> 1][(K) & 1] : o2[4 + (((K) - 8) >> 1)][((K) - 8) & 1])

__global__ void __launch_bounds__(256) edge1_k(const _Float16* __restrict__ h1,
                                               const float* __restrict__ al,
                                               const float* __restrict__ ar,
                                               const int* __restrict__ fillArr,
                                               const unsigned short* __restrict__ srcs,
                                               const float* __restrict__ b1,
                                               _Float16* __restrict__ h2o) {
    int i = (blockIdx.x * blockDim.x + threadIdx.x) >> 6;
    int l = threadIdx.x & 63;
    if (i >= N_NODES) return;
    int c16 = l & 7;
    int head = c16 >> 2;
    int sub = l >> 3;

    const f16x8* rowi = (const f16x8*)(h1 + (size_t)i * 128);
    f16x8 hiA = rowi[c16 * 2], hiB = rowi[c16 * 2 + 1];
    float ari = ar[i * 2 + head];
    int cnt = fillArr[i] + 1;
    int start = i << 6;
    int end = start + ((cnt + 7) & ~7);
    float s = 0.f;
    f32x2 o2[8];
#pragma unroll
    for (int k = 0; k < 8; ++k) o2[k] = (f32x2){0.f, 0.f};

    int p = start + sub + 16;
    int j0 = srcs[start + sub];
    int j1 = srcs[start + sub + 8];
    const f16x8* r0p = (const f16x8*)(h1 + (size_t)j0 * 128);
    const f16x8* r1p = (const f16x8*)(h1 + (size_t)j1 * 128);
    f16x8 qA0 = r0p[c16 * 2], qB0 = r0p[c16 * 2 + 1];
    f16x8 qA1 = r1p[c16 * 2], qB1 = r1p[c16 * 2 + 1];
    float a0 = al[j0 * 2 + head];
    float a1 = al[j1 * 2 + head];

    for (int pb = start; pb < end; pb += 8) {
        float part = dot8_f16(hiA, qA0) + dot8_f16(hiB, qB0);
        part += __shfl_xor(part, 1);
        part += __shfl_xor(part, 2);
        float a = (a0 + ari) * sigmoidf_fast(part);
        float w = __expf(leaky_clamp(a));
        s += w;
        f32x2 w2 = (f32x2){w, w};
#pragma unroll
        for (int k = 0; k < 4; ++k) {
            f32x2 hv;
            hv[0] = (float)qA0[2 * k]; hv[1] = (float)qA0[2 * k + 1];
            o2[k] = w2 * hv + o2[k];
        }
#pragma unroll
        for (int k = 0; k < 4; ++k) {
            f32x2 hv;
            hv[0] = (float)qB0[2 * k]; hv[1] = (float)qB0[2 * k + 1];
            o2[4 + k] = w2 * hv + o2[4 + k];
        }
        qA0 = qA1; qB0 = qB1; a0 = a1;
        int jn = srcs[p]; p += 8;
        const f16x8* rn = (const f16x8*)(h1 + (size_t)jn * 128);
        qA1 = rn[c16 * 2]; qB1 = rn[c16 * 2 + 1];
        a1 = al[jn * 2 + head];
    }
#pragma unroll
    for (int m = 8; m < 64; m <<= 1) {
        s += __shfl_xor(s, m);
#pragma unroll
        for (int k = 0; k < 8; ++k) {
            o2[k][0] += __shfl_xor(o2[k][0], m);
            o2[k][1] += __shfl_xor(o2[k][1], m);
        }
    }
    if (l < 8) {
        float inv = 1.f / (s + 1e-16f);
        f16x8 rA, rB;
#pragma unroll
        for (int k = 0; k < 16; ++k) {
            float r = OVAL(k) * inv + b1[l * 16 + k];
            r = (r > 0.f) ? r : (__expf(r) - 1.f);
            if (k < 8) rA[k] = (_Float16)r; else rB[k - 8] = (_Float16)r;
        }
        f16x8* dst = (f16x8*)(h2o + (size_t)i * 128);
        dst[l * 2] = rA;
        dst[l * 2 + 1] = rB;
    }
}

__global__ void __launch_bounds__(256) edge23_k(const _Float16* __restrict__ hcat,
                                                const float* __restrict__ alc,
                                                const float* __restrict__ arc,
                                                const int* __restrict__ fillArr,
                                                const unsigned short* __restrict__ srcs,
                                                const float* __restrict__ bmu,
                                                const float* __restrict__ bls,
                                                float* __restrict__ out) {
    int i = (blockIdx.x * blockDim.x + threadIdx.x) >> 6;
    int l = threadIdx.x & 63;
    if (i >= N_NODES) return;
    int c16 = l & 7;
    int g = c16 >> 1;
    int sub = l >> 3;

    const f16x8* rowi = (const f16x8*)(hcat + (size_t)i * 128);
    f16x8 hiA = rowi[c16 * 2], hiB = rowi[c16 * 2 + 1];
    float ari = arc[i * 4 + g];
    int cnt = fillArr[i] + 1;
    int start = i << 6;
    int end = start + ((cnt + 7) & ~7);
    float s = 0.f;
    f32x2 o2[8];
#pragma unroll
    for (int k = 0; k < 8; ++k) o2[k] = (f32x2){0.f, 0.f};

    int p = start + sub + 16;
    int j0 = srcs[start + sub];
    int j1 = srcs[start + sub + 8];
    const f16x8* r0p = (const f16x8*)(hcat + (size_t)j0 * 128);
    const f16x8* r1p = (const f16x8*)(hcat + (size_t)j1 * 128);
    f16x8 qA0 = r0p[c16 * 2], qB0 = r0p[c16 * 2 + 1];
    f16x8 qA1 = r1p[c16 * 2], qB1 = r1p[c16 * 2 + 1];
    float a0 = alc[j0 * 4 + g];
    float a1 = alc[j1 * 4 + g];

    for (int pb = start; pb < end; pb += 8) {
        float part = dot8_f16(hiA, qA0) + dot8_f16(hiB, qB0);
        part += __shfl_xor(part, 1);
        float a = (a0 + ari) * sigmoidf_fast(part);
        float w = __expf(leaky_clamp(a));
        s += w;
        f32x2 w2 = (f32x2){w, w};
#pragma unroll
        for (int k = 0; k < 4; ++k) {
            f32x2 hv;
            hv[0] = (float)qA0[2 * k]; hv[1] = (float)qA0[2 * k + 1];
            o2[k] = w2 * hv + o2[k];
        }
#pragma unroll
        for (int k = 0; k < 4; ++k) {
            f32x2 hv;
            hv[0] = (float)qB0[2 * k]; hv[1] = (float)qB0[2 * k + 1];
            o2[4 + k] = w2 * hv + o2[4 + k];
        }
        qA0 = qA1; qB0 = qB1; a0 = a1;
        int jn = srcs[p]; p += 8;
        const f16x8* rn = (const f16x8*)(hcat + (size_t)jn * 128);
        qA1 = rn[c16 * 2]; qB1 = rn[c16 * 2 + 1];
        a1 = alc[jn * 4 + g];
    }
#pragma unroll
    for (int m = 8; m < 64; m <<= 1) {
        s += __shfl_xor(s, m);
#pragma unroll
        for (int k = 0; k < 8; ++k) {
            o2[k][0] += __shfl_xor(o2[k][0], m);
            o2[k][1] += __shfl_xor(o2[k][1], m);
        }
    }
    if (l < 8) {
        float inv = 1.f / (s + 1e-16f);
        int br = l >> 2;
        int cIn = (l & 3) * 16;
        const float* b = br ? bls : bmu;
        float* dst = out + (size_t)br * (N_NODES * 64) + (size_t)i * 64 + cIn;
#pragma unroll
        for (int v4 = 0; v4 < 4; ++v4) {
            float4 bv = ((const float4*)(b + cIn))[v4];
            float4 r;
            r.x = OVAL(v4 * 4 + 0) * inv + bv.x;
            r.y = OVAL(v4 * 4 + 1) * inv + bv.y;
            r.z = OVAL(v4 * 4 + 2) * inv + bv.z;
            r.w = OVAL(v4 * 4 + 3) * inv + bv.w;
            ((float4*)dst)[v4] = r;
        }
    }
}

// ---------------------------------------------------------------- launcher

extern "C" void kernel_launch(void* const* d_in, const int* in_sizes, int n_in,
                              void* d_out, int out_size, void* d_ws, size_t ws_size,
                              hipStream_t stream) {
    const float* x      = (const float*)d_in[0];
    const int*   ei     = (const int*)d_in[1];
    const float* W1     = (const float*)d_in[2];
    const float* att_l1 = (const float*)d_in[3];
    const float* att_r1 = (const float*)d_in[4];
    const float* b1     = (const float*)d_in[5];
    const float* Wmu    = (const float*)d_in[6];
    const float* attlmu = (const float*)d_in[7];
    const float* attrmu = (const float*)d_in[8];
    const float* bmu    = (const float*)d_in[9];
    const float* Wls    = (const float*)d_in[10];
    const float* attlls = (const float*)d_in[11];
    const float* attrls = (const float*)d_in[12];
    const float* bls    = (const float*)d_in[13];
    float* out = (float*)d_out;

    _Float16* h1   = (_Float16*)d_ws;                      // TROWS*128 halfs
    _Float16* hcat = h1 + (size_t)TROWS * 128;             // TROWS*128 halfs
    _Float16* h2   = hcat + (size_t)TROWS * 128;           // NROWS*128 halfs
    float* al1   = (float*)(h2 + (size_t)NROWS * 128);     // TROWS*2
    float* ar1   = al1 + TROWS * 2;                        // TROWS*2
    float* alc   = ar1 + TROWS * 2;                        // TROWS*4
    float* arc   = alc + TROWS * 4;                        // TROWS*4
    // fillArr and srcs contiguous: ONE 0xFF clear gives fill=-1 and
    // srcs=0xFFFF (sentinel) including the over-prefetch tail.
    int* fillArr = (int*)(arc + TROWS * 4);                // 50,048 ints
    unsigned short* srcs = (unsigned short*)(fillArr + 50048);  // 3,200,128 ushorts
    _Float16* Bt1 = (_Float16*)(srcs + 3200128);           // 128*128 halfs (32 KB)
    _Float16* Bt2 = Bt1 + 128 * 128;                       // 128*128 halfs (32 KB)

    // clear (0xFF over fillArr+srcs) + one-time weight transpose/swizzle prep
    init_k<<<CLEAR_BLOCKS + PREP_BLOCKS, 256, 0, stream>>>((uint4*)fillArr,
                                                           W1, Wmu, Wls, Bt1, Bt2);

    // fused: gemm1 (blocks 0..781, 16 KB LDS, LONG blocks first) + scatter
    g1s_k<<<GEMM_TILES + NCHUNK * NPART, 256, 0, stream>>>(x, Bt1, att_l1, att_r1,
                                                           h1, al1, ar1,
                                                           ei, fillArr, srcs);

    int nblocks = (N_NODES + 3) / 4;       // edge kernels: 4 waves (nodes) / block
    edge1_k<<<nblocks, 256, 0, stream>>>(h1, al1, ar1, fillArr, srcs, b1, h2);

    gemm2_k<<<GEMM_TILES, 256, 0, stream>>>(h2, Bt2, attlmu, attrmu, attlls, attrls,
                                            hcat, alc, arc);
    edge23_k<<<nblocks, 256, 0, stream>>>(hcat, alc, arc, fillArr, srcs, bmu, bls, out);
}

// Round 14
// 243.002 us; speedup vs baseline: 1.0163x; 1.0153x over previous
//
#include <hip/hip_runtime.h>
#include <math.h>

#define N_NODES 50000
#define N_EDGES 800000
#define ETOT    (N_EDGES + N_NODES)
#define GEMM_TILES ((N_NODES + 63) / 64)      // 782 (covers 50048 rows)
#define NROWS 50048                            // gemm-written rows
#define TROWS 65536                            // gather-table rows (incl sentinel)
#define SENT_ROW 65535                         // sentinel row (legacy; pads now masked)
#define NPART 8
#define PART_SIZE (N_NODES / NPART)           // 6250
#define CHUNK_EDGES 2048
#define NCHUNK ((ETOT + CHUNK_EDGES - 1) / CHUNK_EDGES)  // 416
// init_k geometry: clear ONLY fillArr (200,192 B = 12,512 uint4) + weight prep.
// srcs is no longer cleared — edge kernels mask tail slots instead (r14).
#define FILL_UINT4 12512
#define CLEAR_BLOCKS ((FILL_UINT4 + 255) / 256)           // 49
#define PREP_BLOCKS 16                                     // 8 per matrix

typedef _Float16 f16x8 __attribute__((ext_vector_type(8)));   // 16 B
typedef _Float16 f16x4 __attribute__((ext_vector_type(4)));   // 8 B
typedef _Float16 f16x2 __attribute__((ext_vector_type(2)));   // 4 B
typedef float    f32x4 __attribute__((ext_vector_type(4)));

// ---------------------------------------------------------------- init: clear + weight prep
// fillArr -> 0xFF (fill=-1: slot = atomicAdd+1 starts at 0; cnt = fill+1).
// Weight prep: 16 trivial blocks, 8 loads -> one 16B store per thread
// (r7 lesson: never a deep serial tail inside another kernel).
// Bt layout, element (k,n):  Bt[n*128 + (((k>>3) ^ (n&7))<<3) + (k&7)]

__global__ void __launch_bounds__(256) init_k(uint4* __restrict__ clr,
                                              const float* __restrict__ W1,
                                              const float* __restrict__ Wmu,
                                              const float* __restrict__ Wls,
                                              _Float16* __restrict__ Bt1,
                                              _Float16* __restrict__ Bt2) {
    int bid = blockIdx.x;
    if (bid < CLEAR_BLOCKS) {
        int id = bid * 256 + threadIdx.x;
        if (id < FILL_UINT4) {
            uint4 v;
            v.x = 0xFFFFFFFFu; v.y = 0xFFFFFFFFu; v.z = 0xFFFFFFFFu; v.w = 0xFFFFFFFFu;
            clr[id] = v;
        }
        return;
    }
    int pb = bid - CLEAR_BLOCKS;           // 0..15
    int which = pb >> 3;                   // 0 -> Bt1 (W1), 1 -> Bt2 ([Wmu|Wls])
    int idx = (pb & 7) * 256 + threadIdx.x;  // 0..2047 = (m, n)
    int n = idx & 127;
    int m = idx >> 7;                      // k-block: k = m*8 + j
    f16x8 v8;
#pragma unroll
    for (int j = 0; j < 8; ++j) {
        int k = m * 8 + j;
        float v = which ? ((n < 64) ? Wmu[k * 64 + n] : Wls[k * 64 + (n - 64)])
                        : W1[k * 128 + n];
        v8[j] = (_Float16)v;
    }
    _Float16* dst = which ? Bt2 : Bt1;
    *(f16x8*)&dst[n * 128 + ((m ^ (n & 7)) << 3)] = v8;
}

// ---------------------------------------------------------------- scatter body (partitioned)
// Atomic-throughput-bound (r9); partitioned beats single-pass via write
// locality. Hidden by overlapping with gemm1 in one dispatch (r11). R12
// lesson: gemm (long) blocks FIRST, scatter (short) backfills (LPT).

__device__ __forceinline__ void scatter_body(int sbid, const int* __restrict__ ei,
                                             int* __restrict__ fillArr,
                                             unsigned short* __restrict__ srcs) {
    int part = sbid & (NPART - 1);
    int chunk = sbid >> 3;
    int lo = part * PART_SIZE, hi = lo + PART_SIZE;
    int base = chunk * CHUNK_EDGES + threadIdx.x;
#pragma unroll
    for (int it = 0; it < CHUNK_EDGES / 256; ++it) {
        int e = base + it * 256;
        if (e >= ETOT) break;
        int d = (e < N_EDGES) ? ei[N_EDGES + e] : (e - N_EDGES);
        if (d >= lo && d < hi) {
            int s = (e < N_EDGES) ? ei[e] : d;
            int pos = (d << 6) + (atomicAdd(&fillArr[d], 1) + 1);
            srcs[pos] = (unsigned short)s;
        }
    }
}

// ---------------------------------------------------------------- MFMA GEMM pieces
// B pre-transposed/swizzled in global (32 KB fp16, fits per-CU L1). No Bsh,
// no transpose, no barriers (Cst slices per-wave-private). 16 KB LDS.

__device__ __forceinline__ void mfma_tile(const f16x8 a[4], const _Float16* __restrict__ Bt,
                                          f32x4 acc[8], int l) {
    int i16 = l & 15, q = l >> 4;
#pragma unroll
    for (int tt = 0; tt < 8; ++tt) acc[tt] = (f32x4){0.f, 0.f, 0.f, 0.f};
#pragma unroll
    for (int kb = 0; kb < 4; ++kb) {
#pragma unroll
        for (int tt = 0; tt < 8; ++tt) {
            int n = tt * 16 + i16;
            int gs = (kb * 4 + q) ^ (n & 7);
            f16x8 b = *(const f16x8*)&Bt[n * 128 + gs * 8];
            acc[tt] = __builtin_amdgcn_mfma_f32_16x16x32_f16(a[kb], b, acc[tt], 0, 0, 0);
        }
    }
}

__device__ __forceinline__ void store_C(const f32x4 acc[8], _Float16* cs,
                                        _Float16* __restrict__ C, int r0, int l) {
    int i16 = l & 15, q = l >> 4;
#pragma unroll
    for (int tt = 0; tt < 8; ++tt)
#pragma unroll
        for (int r = 0; r < 4; ++r)
            cs[(q * 4 + r) * 128 + tt * 16 + i16] = (_Float16)acc[tt][r];
#pragma unroll
    for (int u = 0; u < 4; ++u) {
        int idx = u * 64 + l;
        int rr = idx >> 4, cc = idx & 15;
        f16x8 v = ((f16x8*)cs)[idx];
        if (r0 + rr >= N_NODES) v = (f16x8)(_Float16)0.f;
        ((f16x8*)(C + (size_t)(r0 + rr) * 128))[cc] = v;
    }
}

// g1s: blocks [0, GEMM_TILES) = gemm1 (x@W1 + fused attn1 epilogue, LONG
// blocks first = LPT); blocks beyond = partitioned scatter backfilling.
// 16 KB LDS keeps scatter occupancy (r11: 35%, fusion net +5.5us vs serial).
__global__ void __launch_bounds__(256) g1s_k(const float* __restrict__ A,
                                             const _Float16* __restrict__ Btg,
                                             const float* __restrict__ att_l,
                                             const float* __restrict__ att_r,
                                             _Float16* __restrict__ C,
                                             float* __restrict__ al,
                                             float* __restrict__ ar,
                                             const int* __restrict__ ei,
                                             int* __restrict__ fillArr,
                                             unsigned short* __restrict__ srcs) {
    __shared__ _Float16 Cst[4][16 * 128];
    if (blockIdx.x >= GEMM_TILES) {
        scatter_body(blockIdx.x - GEMM_TILES, ei, fillArr, srcs);
        return;
    }
    int t = threadIdx.x;
    int wave = t >> 6, l = t & 63;
    int i16 = l & 15, q = l >> 4;
    float attL[8], attR[8];
#pragma unroll
    for (int tt = 0; tt < 8; ++tt) {
        int col = tt * 16 + i16;
        attL[tt] = att_l[col];
        attR[tt] = att_r[col];
    }
    int r0 = blockIdx.x * 64 + wave * 16;
    const float* ar_ = A + (size_t)min(r0 + i16, N_NODES - 1) * 128;
    f16x8 a[4];
#pragma unroll
    for (int kb = 0; kb < 4; ++kb) {
        float4 u = ((const float4*)(ar_ + kb * 32 + q * 8))[0];
        float4 v = ((const float4*)(ar_ + kb * 32 + q * 8))[1];
        f16x8 t8;
        t8[0] = (_Float16)u.x; t8[1] = (_Float16)u.y;
        t8[2] = (_Float16)u.z; t8[3] = (_Float16)u.w;
        t8[4] = (_Float16)v.x; t8[5] = (_Float16)v.y;
        t8[6] = (_Float16)v.z; t8[7] = (_Float16)v.w;
        a[kb] = t8;
    }
    f32x4 acc[8];
    mfma_tile(a, Btg, acc, l);
    store_C(acc, &Cst[wave][0], C, r0, l);
    float pl[2][4], pr[2][4];
#pragma unroll
    for (int h = 0; h < 2; ++h)
#pragma unroll
        for (int r = 0; r < 4; ++r) {
            float sl = 0.f, sr = 0.f;
#pragma unroll
            for (int k = 0; k < 4; ++k) {
                float v = acc[h * 4 + k][r];
                sl += v * attL[h * 4 + k];
                sr += v * attR[h * 4 + k];
            }
            pl[h][r] = sl; pr[h][r] = sr;
        }
#pragma unroll
    for (int m = 1; m < 16; m <<= 1) {
#pragma unroll
        for (int h = 0; h < 2; ++h)
#pragma unroll
            for (int r = 0; r < 4; ++r) {
                pl[h][r] += __shfl_xor(pl[h][r], m);
                pr[h][r] += __shfl_xor(pr[h][r], m);
            }
    }
    if (i16 == 0) {
#pragma unroll
        for (int h = 0; h < 2; ++h)
#pragma unroll
            for (int r = 0; r < 4; ++r) {
                int row = r0 + q * 4 + r;
                al[row * 2 + h] = pl[h][r];
                ar[row * 2 + h] = pr[h][r];
            }
    }
    if (blockIdx.x == 0) {
        if (t < 16) ((f16x8*)(C + (size_t)SENT_ROW * 128))[t] = (f16x8)(_Float16)0.f;
        else if (t == 16) {
            al[SENT_ROW * 2] = -1e30f; al[SENT_ROW * 2 + 1] = -1e30f;
            ar[SENT_ROW * 2] = 0.f;    ar[SENT_ROW * 2 + 1] = 0.f;
        }
    }
}

// gemm2: A fp16 h2, B = Bt2 (pre-swizzled [Wmu|Wls]); fused attn23 epilogue.
__global__ void __launch_bounds__(256) gemm2_k(const _Float16* __restrict__ A,
                                               const _Float16* __restrict__ Btg,
                                               const float* __restrict__ attlmu,
                                               const float* __restrict__ attrmu,
                                               const float* __restrict__ attlls,
                                               const float* __restrict__ attrls,
                                               _Float16* __restrict__ C,
                                               float* __restrict__ alc,
                                               float* __restrict__ arc) {
    __shared__ _Float16 Cst[4][16 * 128];
    int t = threadIdx.x;
    int wave = t >> 6, l = t & 63;
    int i16 = l & 15, q = l >> 4;
    float attL[8], attR[8];
#pragma unroll
    for (int tt = 0; tt < 8; ++tt) {
        int col = tt * 16 + i16;
        const float* la = (tt < 4) ? attlmu : attlls;
        const float* ra = (tt < 4) ? attrmu : attrls;
        attL[tt] = la[col & 63];
        attR[tt] = ra[col & 63];
    }
    int r0 = blockIdx.x * 64 + wave * 16;
    const _Float16* ar_ = A + (size_t)min(r0 + i16, N_NODES - 1) * 128;
    f16x8 a[4];
#pragma unroll
    for (int kb = 0; kb < 4; ++kb)
        a[kb] = *(const f16x8*)(ar_ + kb * 32 + q * 8);
    f32x4 acc[8];
    mfma_tile(a, Btg, acc, l);
    store_C(acc, &Cst[wave][0], C, r0, l);
    float pl[4][4], pr[4][4];
#pragma unroll
    for (int g = 0; g < 4; ++g)
#pragma unroll
        for (int r = 0; r < 4; ++r) {
            float sl = 0.f, sr = 0.f;
#pragma unroll
            for (int k = 0; k < 2; ++k) {
                float v = acc[g * 2 + k][r];
                sl += v * attL[g * 2 + k];
                sr += v * attR[g * 2 + k];
            }
            pl[g][r] = sl; pr[g][r] = sr;
        }
#pragma unroll
    for (int m = 1; m < 16; m <<= 1) {
#pragma unroll
        for (int g = 0; g < 4; ++g)
#pragma unroll
            for (int r = 0; r < 4; ++r) {
                pl[g][r] += __shfl_xor(pl[g][r], m);
                pr[g][r] += __shfl_xor(pr[g][r], m);
            }
    }
    if (i16 == 0) {
#pragma unroll
        for (int g = 0; g < 4; ++g)
#pragma unroll
            for (int r = 0; r < 4; ++r) {
                int row = r0 + q * 4 + r;
                alc[row * 4 + g] = pl[g][r];
                arc[row * 4 + g] = pr[g][r];
            }
    }
    if (blockIdx.x == 0) {
        if (t < 16) ((f16x8*)(C + (size_t)SENT_ROW * 128))[t] = (f16x8)(_Float16)0.f;
        else if (t == 16) {
#pragma unroll
            for (int g = 0; g < 4; ++g) {
                alc[SENT_ROW * 4 + g] = -1e30f;
                arc[SENT_ROW * 4 + g] = 0.f;
            }
        }
    }
}

// ---------------------------------------------------------------- edge aggregation
// 8 lanes per edge, 8 edges/iter, 2-deep pipeline with rotation by movs
// (r11 scalar form — measured best; r13 pk_fma was null). ROUND-14: srcs is
// NOT pre-cleared; tail slots are masked instead: gathered index clamped to a
// real row (garbage ushort would read unwritten/NaN rows; clamp keeps values
// finite so w=0 annihilates), and w zeroed for slot >= cnt. Bit-identical
// output (pads contributed w=0 via sentinel before). Lessons: (r3) big
// unroll -> occupancy -16pt; (r5) persistent waves -22pt; (r7) alien-work
// fusion wrecks codegen.

__device__ __forceinline__ float sigmoidf_fast(float x) {
    return 1.f / (1.f + __expf(-x));
}

__device__ __forceinline__ float dot8_f16(f16x8 a, f16x8 b) {
    float part = 0.f;
#if __has_builtin(__builtin_amdgcn_fdot2)
    f16x2* pa = (f16x2*)&a;
    f16x2* pb = (f16x2*)&b;
#pragma unroll
    for (int kk = 0; kk < 4; ++kk)
        part = __builtin_amdgcn_fdot2(pa[kk], pb[kk], part, false);
#else
#pragma unroll
    for (int kk = 0; kk < 8; ++kk) part += (float)a[kk] * (float)b[kk];
#endif
    return part;
}

__device__ __forceinline__ float leaky_clamp(float x) {
    return __builtin_amdgcn_fmed3f(x, 0.2f * x, 60.f);
}

__global__ void __launch_bounds__(256) edge1_k(const _Float16* __restrict__ h1,
                                               const float* __restrict__ al,
                                               const float* __restrict__ ar,
                                               const int* __restrict__ fillArr,
                                               const unsigned short* __restrict__ srcs,
                                               const float* __restrict__ b1,
                                               _Float16* __restrict__ h2o) {
    int i = (blockIdx.x * blockDim.x + threadIdx.x) >> 6;
    int l = threadIdx.x & 63;
    if (i >= N_NODES) return;
    int c16 = l & 7;
    int head = c16 >> 2;
    int sub = l >> 3;

    const f16x8* rowi = (const f16x8*)(h1 + (size_t)i * 128);
    f16x8 hiA = rowi[c16 * 2], hiB = rowi[c16 * 2 + 1];
    float ari = ar[i * 2 + head];
    int cnt = fillArr[i] + 1;
    int start = i << 6;
    int end = start + ((cnt + 7) & ~7);
    int climit = start + cnt;            // consumed slot pb+sub valid iff < climit
    float s = 0.f;
    float o[16];
#pragma unroll
    for (int k = 0; k < 16; ++k) o[k] = 0.f;

    int p = start + sub + 16;
    int j0 = min((int)srcs[start + sub], N_NODES - 1);
    int j1 = min((int)srcs[start + sub + 8], N_NODES - 1);
    const f16x8* r0p = (const f16x8*)(h1 + (size_t)j0 * 128);
    const f16x8* r1p = (const f16x8*)(h1 + (size_t)j1 * 128);
    f16x8 qA0 = r0p[c16 * 2], qB0 = r0p[c16 * 2 + 1];
    f16x8 qA1 = r1p[c16 * 2], qB1 = r1p[c16 * 2 + 1];
    float a0 = al[j0 * 2 + head];
    float a1 = al[j1 * 2 + head];

    for (int pb = start; pb < end; pb += 8) {
        float part = dot8_f16(hiA, qA0) + dot8_f16(hiB, qB0);
        part += __shfl_xor(part, 1);
        part += __shfl_xor(part, 2);
        float a = (a0 + ari) * sigmoidf_fast(part);
        float w = __expf(leaky_clamp(a));
        w = (pb + sub < climit) ? w : 0.f;   // tail mask (pads, uncleaned srcs)
        s += w;
#pragma unroll
        for (int k = 0; k < 8; ++k) o[k] += w * (float)qA0[k];
#pragma unroll
        for (int k = 0; k < 8; ++k) o[8 + k] += w * (float)qB0[k];
        qA0 = qA1; qB0 = qB1; a0 = a1;
        int jn = min((int)srcs[p], N_NODES - 1); p += 8;
        const f16x8* rn = (const f16x8*)(h1 + (size_t)jn * 128);
        qA1 = rn[c16 * 2]; qB1 = rn[c16 * 2 + 1];
        a1 = al[jn * 2 + head];
    }
#pragma unroll
    for (int m = 8; m < 64; m <<= 1) {
        s += __shfl_xor(s, m);
#pragma unroll
        for (int k = 0; k < 16; ++k) o[k] += __shfl_xor(o[k], m);
    }
    if (l < 8) {
        float inv = 1.f / (s + 1e-16f);
        f16x8 rA, rB;
#pragma unroll
        for (int k = 0; k < 16; ++k) {
            float r = o[k] * inv + b1[l * 16 + k];
            r = (r > 0.f) ? r : (__expf(r) - 1.f);
            if (k < 8) rA[k] = (_Float16)r; else rB[k - 8] = (_Float16)r;
        }
        f16x8* dst = (f16x8*)(h2o + (size_t)i * 128);
        dst[l * 2] = rA;
        dst[l * 2 + 1] = rB;
    }
}

__global__ void __launch_bounds__(256) edge23_k(const _Float16* __restrict__ hcat,
                                                const float* __restrict__ alc,
                                                const float* __restrict__ arc,
                                                const int* __restrict__ fillArr,
                                                const unsigned short* __restrict__ srcs,
                                                const float* __restrict__ bmu,
                                                const float* __restrict__ bls,
                                                float* __restrict__ out) {
    int i = (blockIdx.x * blockDim.x + threadIdx.x) >> 6;
    int l = threadIdx.x & 63;
    if (i >= N_NODES) return;
    int c16 = l & 7;
    int g = c16 >> 1;
    int sub = l >> 3;

    const f16x8* rowi = (const f16x8*)(hcat + (size_t)i * 128);
    f16x8 hiA = rowi[c16 * 2], hiB = rowi[c16 * 2 + 1];
    float ari = arc[i * 4 + g];
    int cnt = fillArr[i] + 1;
    int start = i << 6;
    int end = start + ((cnt + 7) & ~7);
    int climit = start + cnt;
    float s = 0.f;
    float o[16];
#pragma unroll
    for (int k = 0; k < 16; ++k) o[k] = 0.f;

    int p = start + sub + 16;
    int j0 = min((int)srcs[start + sub], N_NODES - 1);
    int j1 = min((int)srcs[start + sub + 8], N_NODES - 1);
    const f16x8* r0p = (const f16x8*)(hcat + (size_t)j0 * 128);
    const f16x8* r1p = (const f16x8*)(hcat + (size_t)j1 * 128);
    f16x8 qA0 = r0p[c16 * 2], qB0 = r0p[c16 * 2 + 1];
    f16x8 qA1 = r1p[c16 * 2], qB1 = r1p[c16 * 2 + 1];
    float a0 = alc[j0 * 4 + g];
    float a1 = alc[j1 * 4 + g];

    for (int pb = start; pb < end; pb += 8) {
        float part = dot8_f16(hiA, qA0) + dot8_f16(hiB, qB0);
        part += __shfl_xor(part, 1);
        float a = (a0 + ari) * sigmoidf_fast(part);
        float w = __expf(leaky_clamp(a));
        w = (pb + sub < climit) ? w : 0.f;   // tail mask
        s += w;
#pragma unroll
        for (int k = 0; k < 8; ++k) o[k] += w * (float)qA0[k];
#pragma unroll
        for (int k = 0; k < 8; ++k) o[8 + k] += w * (float)qB0[k];
        qA0 = qA1; qB0 = qB1; a0 = a1;
        int jn = min((int)srcs[p], N_NODES - 1); p += 8;
        const f16x8* rn = (const f16x8*)(hcat + (size_t)jn * 128);
        qA1 = rn[c16 * 2]; qB1 = rn[c16 * 2 + 1];
        a1 = alc[jn * 4 + g];
    }
#pragma unroll
    for (int m = 8; m < 64; m <<= 1) {
        s += __shfl_xor(s, m);
#pragma unroll
        for (int k = 0; k < 16; ++k) o[k] += __shfl_xor(o[k], m);
    }
    if (l < 8) {
        float inv = 1.f / (s + 1e-16f);
        int br = l >> 2;
        int cIn = (l & 3) * 16;
        const float* b = br ? bls : bmu;
        float* dst = out + (size_t)br * (N_NODES * 64) + (size_t)i * 64 + cIn;
#pragma unroll
        for (int v4 = 0; v4 < 4; ++v4) {
            float4 bv = ((const float4*)(b + cIn))[v4];
            float4 r;
            r.x = o[v4 * 4 + 0] * inv + bv.x;
            r.y = o[v4 * 4 + 1] * inv + bv.y;
            r.z = o[v4 * 4 + 2] * inv + bv.z;
            r.w = o[v4 * 4 + 3] * inv + bv.w;
            ((float4*)dst)[v4] = r;
        }
    }
}

// ---------------------------------------------------------------- launcher

extern "C" void kernel_launch(void* const* d_in, const int* in_sizes, int n_in,
                              void* d_out, int out_size, void* d_ws, size_t ws_size,
                              hipStream_t stream) {
    const float* x      = (const float*)d_in[0];
    const int*   ei     = (const int*)d_in[1];
    const float* W1     = (const float*)d_in[2];
    const float* att_l1 = (const float*)d_in[3];
    const float* att_r1 = (const float*)d_in[4];
    const float* b1     = (const float*)d_in[5];
    const float* Wmu    = (const float*)d_in[6];
    const float* attlmu = (const float*)d_in[7];
    const float* attrmu = (const float*)d_in[8];
    const float* bmu    = (const float*)d_in[9];
    const float* Wls    = (const float*)d_in[10];
    const float* attlls = (const float*)d_in[11];
    const float* attrls = (const float*)d_in[12];
    const float* bls    = (const float*)d_in[13];
    float* out = (float*)d_out;

    _Float16* h1   = (_Float16*)d_ws;                      // TROWS*128 halfs
    _Float16* hcat = h1 + (size_t)TROWS * 128;             // TROWS*128 halfs
    _Float16* h2   = hcat + (size_t)TROWS * 128;           // NROWS*128 halfs
    float* al1   = (float*)(h2 + (size_t)NROWS * 128);     // TROWS*2
    float* ar1   = al1 + TROWS * 2;                        // TROWS*2
    float* alc   = ar1 + TROWS * 2;                        // TROWS*4
    float* arc   = alc + TROWS * 4;                        // TROWS*4
    int* fillArr = (int*)(arc + TROWS * 4);                // 50,048 ints (0xFF init)
    unsigned short* srcs = (unsigned short*)(fillArr + 50048);  // 3,200,128 ushorts (UNcleared)
    _Float16* Bt1 = (_Float16*)(srcs + 3200128);           // 128*128 halfs (32 KB)
    _Float16* Bt2 = Bt1 + 128 * 128;                       // 128*128 halfs (32 KB)

    // clear fillArr (0xFF) + one-time weight transpose/swizzle prep (65 blocks)
    init_k<<<CLEAR_BLOCKS + PREP_BLOCKS, 256, 0, stream>>>((uint4*)fillArr,
                                                           W1, Wmu, Wls, Bt1, Bt2);

    // fused: gemm1 (blocks 0..781, 16 KB LDS, LONG blocks first) + scatter
    g1s_k<<<GEMM_TILES + NCHUNK * NPART, 256, 0, stream>>>(x, Bt1, att_l1, att_r1,
                                                           h1, al1, ar1,
                                                           ei, fillArr, srcs);

    int nblocks = (N_NODES + 3) / 4;       // edge kernels: 4 waves (nodes) / block
    edge1_k<<<nblocks, 256, 0, stream>>>(h1, al1, ar1, fillArr, srcs, b1, h2);

    gemm2_k<<<GEMM_TILES, 256, 0, stream>>>(h2, Bt2, attlmu, attrmu, attlls, attrls,
                                            hcat, alc, arc);
    edge23_k<<<nblocks, 256, 0, stream>>>(hcat, alc, arc, fillArr, srcs, bmu, bls, out);
}